// Round 2
// baseline (109.247 us; speedup 1.0000x reference)
//
#include <hip/hip_runtime.h>
#include <math.h>

// GyroLoss: fused so3_exp / bmtm / so3_log / Huber-mean over (64, 8192) rows.
// Memory-bound: 50.3 MB in, 4 B out -> floor ~8 us @ 6.3 TB/s.
// R2: float4 LDS staging (was scalar dword), fast trig (__sincosf),
//     sin(acos(c)) -> sqrt(1-c^2) identity kills sinf entirely.

namespace {
constexpr int kN = 64;
constexpr int kT = 8192;
constexpr int kN0 = 5;
constexpr int kRows = kN * kT;              // 524288
constexpr int kRowsPerBlock = 256;          // == blockDim.x
constexpr int kXs4 = kRowsPerBlock * 9 / 4;   // 576 float4 per block chunk
constexpr int kHx4 = kRowsPerBlock * 15 / 4;  // 960 float4 per block chunk
// out = W * HUBER^2 * mean = 25 * sum / (64 * 8187 * 15)
constexpr float kScale = (float)(25.0 / ((double)kN * (double)(kT - kN0) * 15.0));
}

// Rodrigues: R = I + A*K + B*K^2, K = skew(x,y,z). Row-major R[9].
__device__ __forceinline__ void so3_exp9(float x, float y, float z, float R[9]) {
    float t2 = x * x + y * y + z * z;
    bool sm = t2 < 1e-8f;
    float st2 = sm ? 1.0f : t2;
    float th = sqrtf(st2);
    float s, c;
    __sincosf(th, &s, &c);  // v_sin_f32/v_cos_f32 — error budget is ~2%, this is ~1e-6
    float A = sm ? (1.0f - t2 * (1.0f / 6.0f)) : (s / th);
    float B = sm ? (0.5f - t2 * (1.0f / 24.0f)) : ((1.0f - c) / st2);
    R[0] = 1.0f - B * (y * y + z * z);
    R[1] = B * x * y - A * z;
    R[2] = B * x * z + A * y;
    R[3] = B * x * y + A * z;
    R[4] = 1.0f - B * (x * x + z * z);
    R[5] = B * y * z - A * x;
    R[6] = B * x * z - A * y;
    R[7] = B * y * z + A * x;
    R[8] = 1.0f - B * (x * x + y * y);
}

// out = so3_log(a^T * b); C[i][k] = sum_j a[3j+i] * b[3j+k]
__device__ __forceinline__ void bmtm_log(const float a[9], const float b[9], float out[3]) {
    float C00 = a[0] * b[0] + a[3] * b[3] + a[6] * b[6];
    float C11 = a[1] * b[1] + a[4] * b[4] + a[7] * b[7];
    float C22 = a[2] * b[2] + a[5] * b[5] + a[8] * b[8];
    float C21 = a[2] * b[1] + a[5] * b[4] + a[8] * b[7];
    float C12 = a[1] * b[2] + a[4] * b[5] + a[7] * b[8];
    float C02 = a[0] * b[2] + a[3] * b[5] + a[6] * b[8];
    float C20 = a[2] * b[0] + a[5] * b[3] + a[8] * b[6];
    float C10 = a[1] * b[0] + a[4] * b[3] + a[7] * b[6];
    float C01 = a[0] * b[1] + a[3] * b[4] + a[6] * b[7];
    float tr = C00 + C11 + C22;
    float cs = 0.5f * (tr - 1.0f);
    cs = fminf(1.0f, fmaxf(-1.0f, cs));
    bool sm = cs > (1.0f - 1e-6f);
    float ang = acosf(sm ? 0.0f : cs);
    // sin(acos(c)) == sqrt(1-c^2): factor = ang / (2*sin(ang)) = 0.5*ang*rsqrt(1-c^2)
    float factor = sm ? 0.5f : 0.5f * ang * rsqrtf(fmaxf(1.0f - cs * cs, 1e-30f));
    out[0] = factor * (C21 - C12);
    out[1] = factor * (C02 - C20);
    out[2] = factor * (C10 - C01);
}

__device__ __forceinline__ float huber_term(float r) {
    float z = r * 200.0f;  // 1/HUBER
    float az = fabsf(z);
    return az < 1.0f ? 0.5f * z * z : az - 0.5f;
}

__global__ __launch_bounds__(256) void gyro_loss_kernel(
    const float* __restrict__ xs, const float* __restrict__ hx,
    float* __restrict__ out) {
    __shared__ __align__(16) float s_xs[kRowsPerBlock * 9];   // 9216 B
    __shared__ __align__(16) float s_hx[kRowsPerBlock * 15];  // 15360 B
    const int tid = threadIdx.x;
    const long base_row = (long)blockIdx.x * kRowsPerBlock;

    // Coalesced float4 staging: 16 B/lane, block chunk bases are 16B-aligned
    // (256*9*4 = 9216 B, 256*15*4 = 15360 B, both %16 == 0).
    const float4* gx4 = reinterpret_cast<const float4*>(xs + base_row * 9);
    const float4* gh4 = reinterpret_cast<const float4*>(hx + base_row * 15);
    float4* sx4 = reinterpret_cast<float4*>(s_xs);
    float4* sh4 = reinterpret_cast<float4*>(s_hx);
#pragma unroll
    for (int i = tid; i < kXs4; i += kRowsPerBlock) sx4[i] = gx4[i];
#pragma unroll
    for (int i = tid; i < kHx4; i += kRowsPerBlock) sh4[i] = gh4[i];
    __syncthreads();

    const int row = (int)base_row + tid;
    const int t = row & (kT - 1);
    float sum = 0.0f;
    if (t >= kN0) {
        const float* x = s_xs + tid * 9;   // stride 9 (odd): conflict-free across 32 banks
        const float* h = s_hx + tid * 15;  // stride 15 (odd): conflict-free
        float Rw[9], Ro[9], Rx[9];
        so3_exp9(x[0], x[1], x[2], Rw);
        so3_exp9(h[0], h[1], h[2], Ro);
        so3_exp9(h[6], h[7], h[8], Rx);
        float l1[3], l3[3];
        bmtm_log(Rw, Ro, l1);
        bmtm_log(Rw, Rx, l3);
        // rs1 = 6 * log(Omegas^T hat_Omegas)
        sum += huber_term(6.0f * l1[0]) + huber_term(6.0f * l1[1]) + huber_term(6.0f * l1[2]);
        // rs2 = 6 * (dv - hat_acc)
        sum += huber_term(6.0f * (x[3] - h[3])) + huber_term(6.0f * (x[4] - h[4])) +
               huber_term(6.0f * (x[5] - h[5]));
        // rs3 = log(Omegas^T hat_Xi)
        sum += huber_term(l3[0]) + huber_term(l3[1]) + huber_term(l3[2]);
        // rs4 = dv - hat_dv
        sum += huber_term(x[3] - h[9]) + huber_term(x[4] - h[10]) + huber_term(x[5] - h[11]);
        // rs5 = dp - hat_dp
        sum += huber_term(x[6] - h[12]) + huber_term(x[7] - h[13]) + huber_term(x[8] - h[14]);
    }

    // wave64 butterfly reduce
#pragma unroll
    for (int off = 32; off > 0; off >>= 1) sum += __shfl_down(sum, off, 64);
    __shared__ float wsum[4];
    const int lane = tid & 63;
    const int w = tid >> 6;
    if (lane == 0) wsum[w] = sum;
    __syncthreads();
    if (tid == 0) {
        float tot = (wsum[0] + wsum[1] + wsum[2] + wsum[3]) * kScale;
        atomicAdd(out, tot);
    }
}

extern "C" void kernel_launch(void* const* d_in, const int* in_sizes, int n_in,
                              void* d_out, int out_size, void* d_ws, size_t ws_size,
                              hipStream_t stream) {
    const float* xs = (const float*)d_in[0];
    const float* hx = (const float*)d_in[1];
    float* out = (float*)d_out;
    // d_out is poisoned to 0xAA before every timed launch -> zero it on-stream.
    hipMemsetAsync(out, 0, sizeof(float), stream);
    gyro_loss_kernel<<<kRows / kRowsPerBlock, kRowsPerBlock, 0, stream>>>(xs, hx, out);
}

// Round 3
// 91.197 us; speedup vs baseline: 1.1979x; 1.1979x over previous
//
#include <hip/hip_runtime.h>
#include <math.h>

// GyroLoss: fused so3_exp / bmtm / so3_log / Huber-mean over (64, 8192) rows.
// R3: the 46 us was 2048 same-address atomicAdds serializing (~22 ns each) at
// the point of coherence — every wave camps until its atomic completes.
// Replace with partials-to-workspace (no contention) + tiny reduce kernel.

namespace {
constexpr int kN = 64;
constexpr int kT = 8192;
constexpr int kN0 = 5;
constexpr int kRows = kN * kT;                // 524288
constexpr int kRowsPerBlock = 256;            // == blockDim.x
constexpr int kBlocks = kRows / kRowsPerBlock;  // 2048
constexpr int kXs4 = kRowsPerBlock * 9 / 4;   // 576 float4 per block chunk
constexpr int kHx4 = kRowsPerBlock * 15 / 4;  // 960 float4 per block chunk
// out = W * HUBER^2 * mean = 25 * sum / (64 * 8187 * 15)
constexpr float kScale = (float)(25.0 / ((double)kN * (double)(kT - kN0) * 15.0));
}

// Rodrigues: R = I + A*K + B*K^2, K = skew(x,y,z). Row-major R[9].
__device__ __forceinline__ void so3_exp9(float x, float y, float z, float R[9]) {
    float t2 = x * x + y * y + z * z;
    bool sm = t2 < 1e-8f;
    float st2 = sm ? 1.0f : t2;
    float th = sqrtf(st2);
    float s, c;
    __sincosf(th, &s, &c);
    float A = sm ? (1.0f - t2 * (1.0f / 6.0f)) : (s / th);
    float B = sm ? (0.5f - t2 * (1.0f / 24.0f)) : ((1.0f - c) / st2);
    R[0] = 1.0f - B * (y * y + z * z);
    R[1] = B * x * y - A * z;
    R[2] = B * x * z + A * y;
    R[3] = B * x * y + A * z;
    R[4] = 1.0f - B * (x * x + z * z);
    R[5] = B * y * z - A * x;
    R[6] = B * x * z - A * y;
    R[7] = B * y * z + A * x;
    R[8] = 1.0f - B * (x * x + y * y);
}

// out = so3_log(a^T * b); C[i][k] = sum_j a[3j+i] * b[3j+k]
__device__ __forceinline__ void bmtm_log(const float a[9], const float b[9], float out[3]) {
    float C00 = a[0] * b[0] + a[3] * b[3] + a[6] * b[6];
    float C11 = a[1] * b[1] + a[4] * b[4] + a[7] * b[7];
    float C22 = a[2] * b[2] + a[5] * b[5] + a[8] * b[8];
    float C21 = a[2] * b[1] + a[5] * b[4] + a[8] * b[7];
    float C12 = a[1] * b[2] + a[4] * b[5] + a[7] * b[8];
    float C02 = a[0] * b[2] + a[3] * b[5] + a[6] * b[8];
    float C20 = a[2] * b[0] + a[5] * b[3] + a[8] * b[6];
    float C10 = a[1] * b[0] + a[4] * b[3] + a[7] * b[6];
    float C01 = a[0] * b[1] + a[3] * b[4] + a[6] * b[7];
    float tr = C00 + C11 + C22;
    float cs = 0.5f * (tr - 1.0f);
    cs = fminf(1.0f, fmaxf(-1.0f, cs));
    bool sm = cs > (1.0f - 1e-6f);
    float ang = acosf(sm ? 0.0f : cs);
    // sin(acos(c)) == sqrt(1-c^2): factor = ang / (2*sin(ang)) = 0.5*ang*rsqrt(1-c^2)
    float factor = sm ? 0.5f : 0.5f * ang * rsqrtf(fmaxf(1.0f - cs * cs, 1e-30f));
    out[0] = factor * (C21 - C12);
    out[1] = factor * (C02 - C20);
    out[2] = factor * (C10 - C01);
}

__device__ __forceinline__ float huber_term(float r) {
    float z = r * 200.0f;  // 1/HUBER
    float az = fabsf(z);
    return az < 1.0f ? 0.5f * z * z : az - 0.5f;
}

__global__ __launch_bounds__(256) void gyro_loss_kernel(
    const float* __restrict__ xs, const float* __restrict__ hx,
    float* __restrict__ partials) {
    __shared__ __align__(16) float s_xs[kRowsPerBlock * 9];   // 9216 B
    __shared__ __align__(16) float s_hx[kRowsPerBlock * 15];  // 15360 B
    const int tid = threadIdx.x;
    const long base_row = (long)blockIdx.x * kRowsPerBlock;

    // Coalesced float4 staging (block chunk bases are 16B-aligned).
    const float4* gx4 = reinterpret_cast<const float4*>(xs + base_row * 9);
    const float4* gh4 = reinterpret_cast<const float4*>(hx + base_row * 15);
    float4* sx4 = reinterpret_cast<float4*>(s_xs);
    float4* sh4 = reinterpret_cast<float4*>(s_hx);
#pragma unroll
    for (int i = tid; i < kXs4; i += kRowsPerBlock) sx4[i] = gx4[i];
#pragma unroll
    for (int i = tid; i < kHx4; i += kRowsPerBlock) sh4[i] = gh4[i];
    __syncthreads();

    const int row = (int)base_row + tid;
    const int t = row & (kT - 1);
    float sum = 0.0f;
    if (t >= kN0) {
        const float* x = s_xs + tid * 9;   // odd stride: conflict-free
        const float* h = s_hx + tid * 15;  // odd stride: conflict-free
        float Rw[9], Ro[9], Rx[9];
        so3_exp9(x[0], x[1], x[2], Rw);
        so3_exp9(h[0], h[1], h[2], Ro);
        so3_exp9(h[6], h[7], h[8], Rx);
        float l1[3], l3[3];
        bmtm_log(Rw, Ro, l1);
        bmtm_log(Rw, Rx, l3);
        sum += huber_term(6.0f * l1[0]) + huber_term(6.0f * l1[1]) + huber_term(6.0f * l1[2]);
        sum += huber_term(6.0f * (x[3] - h[3])) + huber_term(6.0f * (x[4] - h[4])) +
               huber_term(6.0f * (x[5] - h[5]));
        sum += huber_term(l3[0]) + huber_term(l3[1]) + huber_term(l3[2]);
        sum += huber_term(x[3] - h[9]) + huber_term(x[4] - h[10]) + huber_term(x[5] - h[11]);
        sum += huber_term(x[6] - h[12]) + huber_term(x[7] - h[13]) + huber_term(x[8] - h[14]);
    }

    // wave64 butterfly reduce
#pragma unroll
    for (int off = 32; off > 0; off >>= 1) sum += __shfl_down(sum, off, 64);
    __shared__ float wsum[4];
    const int lane = tid & 63;
    const int w = tid >> 6;
    if (lane == 0) wsum[w] = sum;
    __syncthreads();
    // One plain store per block — no same-address atomic contention.
    if (tid == 0) partials[blockIdx.x] = wsum[0] + wsum[1] + wsum[2] + wsum[3];
}

__global__ __launch_bounds__(256) void reduce_kernel(const float* __restrict__ partials,
                                                     float* __restrict__ out) {
    const int tid = threadIdx.x;
    float sum = 0.0f;
#pragma unroll
    for (int i = 0; i < kBlocks / 256; ++i) sum += partials[tid + i * 256];
#pragma unroll
    for (int off = 32; off > 0; off >>= 1) sum += __shfl_down(sum, off, 64);
    __shared__ float wsum[4];
    if ((tid & 63) == 0) wsum[tid >> 6] = sum;
    __syncthreads();
    if (tid == 0) out[0] = (wsum[0] + wsum[1] + wsum[2] + wsum[3]) * kScale;
}

extern "C" void kernel_launch(void* const* d_in, const int* in_sizes, int n_in,
                              void* d_out, int out_size, void* d_ws, size_t ws_size,
                              hipStream_t stream) {
    const float* xs = (const float*)d_in[0];
    const float* hx = (const float*)d_in[1];
    float* out = (float*)d_out;
    float* partials = (float*)d_ws;  // 2048 floats; every slot written each launch
    gyro_loss_kernel<<<kBlocks, kRowsPerBlock, 0, stream>>>(xs, hx, partials);
    reduce_kernel<<<1, 256, 0, stream>>>(partials, out);
}

// Round 4
// 90.545 us; speedup vs baseline: 1.2066x; 1.0072x over previous
//
#include <hip/hip_runtime.h>
#include <math.h>

// GyroLoss: fused so3_exp / bmtm / so3_log / Huber-mean over (64, 8192) rows.
// R4: trim kernel epilogue — per-wave partial store (no final barrier/LDS
// round-trip), float4 reduce kernel. Probing the harness floor: timed window
// is dominated by the harness's 268 MB ws-poison fill (42 us @ 80% HBM peak)
// + 50 MB input restore, which we cannot touch.

namespace {
constexpr int kN = 64;
constexpr int kT = 8192;
constexpr int kN0 = 5;
constexpr int kRows = kN * kT;                  // 524288
constexpr int kRowsPerBlock = 256;              // == blockDim.x
constexpr int kBlocks = kRows / kRowsPerBlock;  // 2048
constexpr int kWavesPerBlock = kRowsPerBlock / 64;  // 4
constexpr int kPartials = kBlocks * kWavesPerBlock; // 8192
constexpr int kXs4 = kRowsPerBlock * 9 / 4;     // 576 float4 per block chunk
constexpr int kHx4 = kRowsPerBlock * 15 / 4;    // 960 float4 per block chunk
// out = W * HUBER^2 * mean = 25 * sum / (64 * 8187 * 15)
constexpr float kScale = (float)(25.0 / ((double)kN * (double)(kT - kN0) * 15.0));
}

// Rodrigues: R = I + A*K + B*K^2, K = skew(x,y,z). Row-major R[9].
__device__ __forceinline__ void so3_exp9(float x, float y, float z, float R[9]) {
    float t2 = x * x + y * y + z * z;
    bool sm = t2 < 1e-8f;
    float st2 = sm ? 1.0f : t2;
    float th = sqrtf(st2);
    float s, c;
    __sincosf(th, &s, &c);
    float A = sm ? (1.0f - t2 * (1.0f / 6.0f)) : (s / th);
    float B = sm ? (0.5f - t2 * (1.0f / 24.0f)) : ((1.0f - c) / st2);
    R[0] = 1.0f - B * (y * y + z * z);
    R[1] = B * x * y - A * z;
    R[2] = B * x * z + A * y;
    R[3] = B * x * y + A * z;
    R[4] = 1.0f - B * (x * x + z * z);
    R[5] = B * y * z - A * x;
    R[6] = B * x * z - A * y;
    R[7] = B * y * z + A * x;
    R[8] = 1.0f - B * (x * x + y * y);
}

// out = so3_log(a^T * b); C[i][k] = sum_j a[3j+i] * b[3j+k]
__device__ __forceinline__ void bmtm_log(const float a[9], const float b[9], float out[3]) {
    float C00 = a[0] * b[0] + a[3] * b[3] + a[6] * b[6];
    float C11 = a[1] * b[1] + a[4] * b[4] + a[7] * b[7];
    float C22 = a[2] * b[2] + a[5] * b[5] + a[8] * b[8];
    float C21 = a[2] * b[1] + a[5] * b[4] + a[8] * b[7];
    float C12 = a[1] * b[2] + a[4] * b[5] + a[7] * b[8];
    float C02 = a[0] * b[2] + a[3] * b[5] + a[6] * b[8];
    float C20 = a[2] * b[0] + a[5] * b[3] + a[8] * b[6];
    float C10 = a[1] * b[0] + a[4] * b[3] + a[7] * b[6];
    float C01 = a[0] * b[1] + a[3] * b[4] + a[6] * b[7];
    float tr = C00 + C11 + C22;
    float cs = 0.5f * (tr - 1.0f);
    cs = fminf(1.0f, fmaxf(-1.0f, cs));
    bool sm = cs > (1.0f - 1e-6f);
    float ang = acosf(sm ? 0.0f : cs);
    // sin(acos(c)) == sqrt(1-c^2): factor = ang/(2 sin ang) = 0.5*ang*rsqrt(1-c^2)
    float factor = sm ? 0.5f : 0.5f * ang * rsqrtf(fmaxf(1.0f - cs * cs, 1e-30f));
    out[0] = factor * (C21 - C12);
    out[1] = factor * (C02 - C20);
    out[2] = factor * (C10 - C01);
}

__device__ __forceinline__ float huber_term(float r) {
    float z = r * 200.0f;  // 1/HUBER
    float az = fabsf(z);
    return az < 1.0f ? 0.5f * z * z : az - 0.5f;
}

__global__ __launch_bounds__(256) void gyro_loss_kernel(
    const float* __restrict__ xs, const float* __restrict__ hx,
    float* __restrict__ partials) {
    __shared__ __align__(16) float s_xs[kRowsPerBlock * 9];   // 9216 B
    __shared__ __align__(16) float s_hx[kRowsPerBlock * 15];  // 15360 B
    const int tid = threadIdx.x;
    const long base_row = (long)blockIdx.x * kRowsPerBlock;

    // Coalesced float4 staging (block chunk bases are 16B-aligned).
    const float4* gx4 = reinterpret_cast<const float4*>(xs + base_row * 9);
    const float4* gh4 = reinterpret_cast<const float4*>(hx + base_row * 15);
    float4* sx4 = reinterpret_cast<float4*>(s_xs);
    float4* sh4 = reinterpret_cast<float4*>(s_hx);
#pragma unroll
    for (int i = tid; i < kXs4; i += kRowsPerBlock) sx4[i] = gx4[i];
#pragma unroll
    for (int i = tid; i < kHx4; i += kRowsPerBlock) sh4[i] = gh4[i];
    __syncthreads();

    const int row = (int)base_row + tid;
    const int t = row & (kT - 1);
    float sum = 0.0f;
    if (t >= kN0) {
        const float* x = s_xs + tid * 9;   // odd stride: conflict-free
        const float* h = s_hx + tid * 15;  // odd stride: conflict-free
        float Rw[9], Ro[9], Rx[9];
        so3_exp9(x[0], x[1], x[2], Rw);
        so3_exp9(h[0], h[1], h[2], Ro);
        so3_exp9(h[6], h[7], h[8], Rx);
        float l1[3], l3[3];
        bmtm_log(Rw, Ro, l1);
        bmtm_log(Rw, Rx, l3);
        sum += huber_term(6.0f * l1[0]) + huber_term(6.0f * l1[1]) + huber_term(6.0f * l1[2]);
        sum += huber_term(6.0f * (x[3] - h[3])) + huber_term(6.0f * (x[4] - h[4])) +
               huber_term(6.0f * (x[5] - h[5]));
        sum += huber_term(l3[0]) + huber_term(l3[1]) + huber_term(l3[2]);
        sum += huber_term(x[3] - h[9]) + huber_term(x[4] - h[10]) + huber_term(x[5] - h[11]);
        sum += huber_term(x[6] - h[12]) + huber_term(x[7] - h[13]) + huber_term(x[8] - h[14]);
    }

    // wave64 butterfly reduce; each wave stores its own partial — no final
    // barrier, no LDS round-trip, no same-address contention.
#pragma unroll
    for (int off = 32; off > 0; off >>= 1) sum += __shfl_down(sum, off, 64);
    if ((tid & 63) == 0) partials[blockIdx.x * kWavesPerBlock + (tid >> 6)] = sum;
}

__global__ __launch_bounds__(256) void reduce_kernel(const float* __restrict__ partials,
                                                     float* __restrict__ out) {
    const int tid = threadIdx.x;
    const float4* p4 = reinterpret_cast<const float4*>(partials);
    float sum = 0.0f;
#pragma unroll
    for (int i = 0; i < kPartials / 4 / 256; ++i) {  // 8 float4 per thread
        float4 v = p4[tid + i * 256];
        sum += (v.x + v.y) + (v.z + v.w);
    }
#pragma unroll
    for (int off = 32; off > 0; off >>= 1) sum += __shfl_down(sum, off, 64);
    __shared__ float wsum[4];
    if ((tid & 63) == 0) wsum[tid >> 6] = sum;
    __syncthreads();
    if (tid == 0) out[0] = (wsum[0] + wsum[1] + wsum[2] + wsum[3]) * kScale;
}

extern "C" void kernel_launch(void* const* d_in, const int* in_sizes, int n_in,
                              void* d_out, int out_size, void* d_ws, size_t ws_size,
                              hipStream_t stream) {
    const float* xs = (const float*)d_in[0];
    const float* hx = (const float*)d_in[1];
    float* out = (float*)d_out;
    float* partials = (float*)d_ws;  // 8192 floats; every slot written each launch
    gyro_loss_kernel<<<kBlocks, kRowsPerBlock, 0, stream>>>(xs, hx, partials);
    reduce_kernel<<<1, 256, 0, stream>>>(partials, out);
}

// Round 5
// 88.471 us; speedup vs baseline: 1.2348x; 1.0234x over previous
//
#include <hip/hip_runtime.h>
#include <math.h>

// GyroLoss: fused so3_exp / bmtm / so3_log / Huber-mean over (64, 8192) rows.
// R5: kill slow libm — full-precision divides (v_div_scale/fmas/fixup ~10 instr
// each, 6/row) and OCML acosf (~25 instr, 2/row) were ~half the kernel's VALU.
// Replace: 1/theta = rsqrtf(t2) (no div, no sqrt); acos -> A&S 4.4.45 poly
// (abs err ~1e-4 rad, budget is 2%). Fixed harness traffic (~63 us: 268 MB
// ws-poison fill + 50 MB input restore) bounds the bench window from below.

namespace {
constexpr int kN = 64;
constexpr int kT = 8192;
constexpr int kN0 = 5;
constexpr int kRows = kN * kT;                  // 524288
constexpr int kRowsPerBlock = 256;              // == blockDim.x
constexpr int kBlocks = kRows / kRowsPerBlock;  // 2048
constexpr int kWavesPerBlock = kRowsPerBlock / 64;   // 4
constexpr int kPartials = kBlocks * kWavesPerBlock;  // 8192
constexpr int kXs4 = kRowsPerBlock * 9 / 4;     // 576 float4 per block chunk
constexpr int kHx4 = kRowsPerBlock * 15 / 4;    // 960 float4 per block chunk
// out = W * HUBER^2 * mean = 25 * sum / (64 * 8187 * 15)
constexpr float kScale = (float)(25.0 / ((double)kN * (double)(kT - kN0) * 15.0));
}

// Abramowitz-Stegun 4.4.45: acos(x) ~ sqrt(1-|x|)*poly(|x|), mirrored for x<0.
// Abs err ~1e-4 rad — error budget here is ~2e-2 relative.
__device__ __forceinline__ float fast_acos(float x) {
    float xa = fabsf(x);
    float p = fmaf(xa, fmaf(xa, fmaf(xa, -0.0187293f, 0.0742610f), -0.2121144f), 1.5707288f);
    float r = sqrtf(fmaxf(1.0f - xa, 0.0f)) * p;
    return x < 0.0f ? 3.14159265f - r : r;
}

// Rodrigues: R = I + A*K + B*K^2, K = skew(x,y,z). Row-major R[9].
// 1/theta via v_rsq_f32: A = s*rth, B = (1-c)*rth^2 — zero divides, zero sqrt.
__device__ __forceinline__ void so3_exp9(float x, float y, float z, float R[9]) {
    float t2 = x * x + y * y + z * z;
    bool sm = t2 < 1e-8f;
    float st2 = sm ? 1.0f : t2;
    float rth = rsqrtf(st2);       // 1/theta
    float th = st2 * rth;          // theta = t2 * (1/theta)
    float s, c;
    __sincosf(th, &s, &c);
    float A = sm ? (1.0f - t2 * (1.0f / 6.0f)) : (s * rth);
    float B = sm ? (0.5f - t2 * (1.0f / 24.0f)) : ((1.0f - c) * rth * rth);
    R[0] = 1.0f - B * (y * y + z * z);
    R[1] = B * x * y - A * z;
    R[2] = B * x * z + A * y;
    R[3] = B * x * y + A * z;
    R[4] = 1.0f - B * (x * x + z * z);
    R[5] = B * y * z - A * x;
    R[6] = B * x * z - A * y;
    R[7] = B * y * z + A * x;
    R[8] = 1.0f - B * (x * x + y * y);
}

// out = so3_log(a^T * b); C[i][k] = sum_j a[3j+i] * b[3j+k]
__device__ __forceinline__ void bmtm_log(const float a[9], const float b[9], float out[3]) {
    float C00 = a[0] * b[0] + a[3] * b[3] + a[6] * b[6];
    float C11 = a[1] * b[1] + a[4] * b[4] + a[7] * b[7];
    float C22 = a[2] * b[2] + a[5] * b[5] + a[8] * b[8];
    float C21 = a[2] * b[1] + a[5] * b[4] + a[8] * b[7];
    float C12 = a[1] * b[2] + a[4] * b[5] + a[7] * b[8];
    float C02 = a[0] * b[2] + a[3] * b[5] + a[6] * b[8];
    float C20 = a[2] * b[0] + a[5] * b[3] + a[8] * b[6];
    float C10 = a[1] * b[0] + a[4] * b[3] + a[7] * b[6];
    float C01 = a[0] * b[1] + a[3] * b[4] + a[6] * b[7];
    float tr = C00 + C11 + C22;
    float cs = 0.5f * (tr - 1.0f);
    cs = fminf(1.0f, fmaxf(-1.0f, cs));
    bool sm = cs > (1.0f - 1e-6f);
    float ang = fast_acos(sm ? 0.0f : cs);
    // sin(acos(c)) == sqrt(1-c^2): factor = ang/(2 sin ang) = 0.5*ang*rsqrt(1-c^2)
    float factor = sm ? 0.5f : 0.5f * ang * rsqrtf(fmaxf(1.0f - cs * cs, 1e-30f));
    out[0] = factor * (C21 - C12);
    out[1] = factor * (C02 - C20);
    out[2] = factor * (C10 - C01);
}

__device__ __forceinline__ float huber_term(float r) {
    float z = r * 200.0f;  // 1/HUBER
    float az = fabsf(z);
    return az < 1.0f ? 0.5f * z * z : az - 0.5f;
}

__global__ __launch_bounds__(256) void gyro_loss_kernel(
    const float* __restrict__ xs, const float* __restrict__ hx,
    float* __restrict__ partials) {
    __shared__ __align__(16) float s_xs[kRowsPerBlock * 9];   // 9216 B
    __shared__ __align__(16) float s_hx[kRowsPerBlock * 15];  // 15360 B
    const int tid = threadIdx.x;
    const long base_row = (long)blockIdx.x * kRowsPerBlock;

    // Coalesced float4 staging (block chunk bases are 16B-aligned).
    const float4* gx4 = reinterpret_cast<const float4*>(xs + base_row * 9);
    const float4* gh4 = reinterpret_cast<const float4*>(hx + base_row * 15);
    float4* sx4 = reinterpret_cast<float4*>(s_xs);
    float4* sh4 = reinterpret_cast<float4*>(s_hx);
#pragma unroll
    for (int i = tid; i < kXs4; i += kRowsPerBlock) sx4[i] = gx4[i];
#pragma unroll
    for (int i = tid; i < kHx4; i += kRowsPerBlock) sh4[i] = gh4[i];
    __syncthreads();

    const int row = (int)base_row + tid;
    const int t = row & (kT - 1);
    float sum = 0.0f;
    if (t >= kN0) {
        const float* x = s_xs + tid * 9;   // odd stride: conflict-free
        const float* h = s_hx + tid * 15;  // odd stride: conflict-free
        float Rw[9], Ro[9], Rx[9];
        so3_exp9(x[0], x[1], x[2], Rw);
        so3_exp9(h[0], h[1], h[2], Ro);
        so3_exp9(h[6], h[7], h[8], Rx);
        float l1[3], l3[3];
        bmtm_log(Rw, Ro, l1);
        bmtm_log(Rw, Rx, l3);
        sum += huber_term(6.0f * l1[0]) + huber_term(6.0f * l1[1]) + huber_term(6.0f * l1[2]);
        sum += huber_term(6.0f * (x[3] - h[3])) + huber_term(6.0f * (x[4] - h[4])) +
               huber_term(6.0f * (x[5] - h[5]));
        sum += huber_term(l3[0]) + huber_term(l3[1]) + huber_term(l3[2]);
        sum += huber_term(x[3] - h[9]) + huber_term(x[4] - h[10]) + huber_term(x[5] - h[11]);
        sum += huber_term(x[6] - h[12]) + huber_term(x[7] - h[13]) + huber_term(x[8] - h[14]);
    }

    // wave64 butterfly reduce; one plain store per wave — no contention.
#pragma unroll
    for (int off = 32; off > 0; off >>= 1) sum += __shfl_down(sum, off, 64);
    if ((tid & 63) == 0) partials[blockIdx.x * kWavesPerBlock + (tid >> 6)] = sum;
}

__global__ __launch_bounds__(256) void reduce_kernel(const float* __restrict__ partials,
                                                     float* __restrict__ out) {
    const int tid = threadIdx.x;
    const float4* p4 = reinterpret_cast<const float4*>(partials);
    float sum = 0.0f;
#pragma unroll
    for (int i = 0; i < kPartials / 4 / 256; ++i) {  // 8 float4 per thread
        float4 v = p4[tid + i * 256];
        sum += (v.x + v.y) + (v.z + v.w);
    }
#pragma unroll
    for (int off = 32; off > 0; off >>= 1) sum += __shfl_down(sum, off, 64);
    __shared__ float wsum[4];
    if ((tid & 63) == 0) wsum[tid >> 6] = sum;
    __syncthreads();
    if (tid == 0) out[0] = (wsum[0] + wsum[1] + wsum[2] + wsum[3]) * kScale;
}

extern "C" void kernel_launch(void* const* d_in, const int* in_sizes, int n_in,
                              void* d_out, int out_size, void* d_ws, size_t ws_size,
                              hipStream_t stream) {
    const float* xs = (const float*)d_in[0];
    const float* hx = (const float*)d_in[1];
    float* out = (float*)d_out;
    float* partials = (float*)d_ws;  // 8192 floats; every slot written each launch
    gyro_loss_kernel<<<kBlocks, kRowsPerBlock, 0, stream>>>(xs, hx, partials);
    reduce_kernel<<<1, 256, 0, stream>>>(partials, out);
}